// Round 1
// baseline (100.232 us; speedup 1.0000x reference)
//
#include <hip/hip_runtime.h>

// PCN reduced recurrence. Only S[13], S[14], Wk[13], Wg matter (information
// flows strictly downward through the layer stack; out = initial S[14]).
//
//   C  = relu(S14) @ Wk13^T              (constant across cycles)
//   Rs = 0.01 * (S14^T > 0)              (constant across cycles)
//   loop 10:
//     e  = s - C
//     g  = W_old^T @ e                   (g[x][y] = sum_c W[c][x]*e[c][y])
//     W  = e .* Rs                       (replaces W)
//     s += 0.01*(relu'(s) - e) .* g
//   out[0:4096]    = S14 (copy)
//   out[4096:8192] = W after 10 cycles
//
// Single 256-thread block on one CU; each thread owns a 4x4 tile, so every
// elementwise op stays in registers. e and W live in LDS (W double-buffered)
// with a float4-granular XOR swizzle (c4 ^= r&15) so the stride-256B column
// reads of the rank-1-update matmul are bank-conflict-free. The c-loop is
// fully unrolled so swizzled addresses fold into ds_read offset immediates.

static constexpr float LRc = 0.01f;

__device__ __forceinline__ int idxEW(int r, int c) {
    // row-major 64x64, float4-granular XOR swizzle by (r & 15)
    return (r << 6) + ((((c >> 2) ^ (r & 15)) << 2) | (c & 3));
}
__device__ __forceinline__ int idxAB(int r, int c) {
    // staging buffers for the C precompute: swizzle by (r>>2)&15
    return (r << 6) + ((((c >> 2) ^ ((r >> 2) & 15)) << 2) | (c & 3));
}

__global__ __launch_bounds__(256)
void pcn_kernel(const float* __restrict__ S,    // (15,64,64)
                const float* __restrict__ Wk,   // (14,64,64)
                const float* __restrict__ Wg,   // (64,64)
                float* __restrict__ out)        // 8192 floats
{
    if (blockIdx.x == 1) {
        // out[0:4096] = S[14] (the reference's `out` — never updated)
        const float4* src = (const float4*)(S + 14 * 4096);
        float4* dst = (float4*)out;
        #pragma unroll
        for (int k = 0; k < 4; ++k)
            dst[threadIdx.x + (k << 8)] = src[threadIdx.x + (k << 8)];
        return;
    }

    __shared__ float Eb[64 * 64];
    __shared__ float Wb[2][64 * 64];

    const int t  = threadIdx.x;
    const int tx = t & 15, ty = t >> 4;
    const int x0 = tx << 2, y0 = ty << 2;   // this thread's 4x4 tile origin

    const float* S13  = S  + 13 * 4096;
    const float* S14  = S  + 14 * 4096;
    const float* Wk13 = Wk + 13 * 4096;

    // ---- stage A = relu(S14), B = Wk13 into Wb[0]/Wb[1] (AB swizzle) ----
    #pragma unroll
    for (int k = 0; k < 16; ++k) {
        int idx = t + (k << 8);
        int r = idx >> 6, cc = idx & 63;
        float a = S14[idx];
        Wb[0][idxAB(r, cc)] = fmaxf(a, 0.f);
        Wb[1][idxAB(r, cc)] = Wk13[idx];
    }

    float s[4][4], Cm[4][4], Rs[4][4], e[4][4], wn[4][4];

    // s = S13 tile
    #pragma unroll
    for (int i = 0; i < 4; ++i) {
        float4 v = *(const float4*)(S13 + (x0 + i) * 64 + y0);
        s[i][0] = v.x; s[i][1] = v.y; s[i][2] = v.z; s[i][3] = v.w;
    }
    // Rs[i][j] = 0.01 * (S14[y0+j][x0+i] > 0)   (= LR * relu'(S14)^T)
    #pragma unroll
    for (int j = 0; j < 4; ++j) {
        float4 v = *(const float4*)(S14 + (y0 + j) * 64 + x0);
        Rs[0][j] = v.x > 0.f ? LRc : 0.f;
        Rs[1][j] = v.y > 0.f ? LRc : 0.f;
        Rs[2][j] = v.z > 0.f ? LRc : 0.f;
        Rs[3][j] = v.w > 0.f ? LRc : 0.f;
    }
    __syncthreads();

    // ---- Cm[x][y] = sum_k relu(S14)[x][k] * Wk13[y][k] ----
    #pragma unroll
    for (int i = 0; i < 4; ++i)
        #pragma unroll
        for (int j = 0; j < 4; ++j) Cm[i][j] = 0.f;

    #pragma unroll
    for (int k = 0; k < 64; k += 4) {
        float a4[4][4], b4[4][4];
        #pragma unroll
        for (int i = 0; i < 4; ++i) {
            float4 v = *(const float4*)&Wb[0][idxAB(x0 + i, k)];
            a4[i][0] = v.x; a4[i][1] = v.y; a4[i][2] = v.z; a4[i][3] = v.w;
        }
        #pragma unroll
        for (int j = 0; j < 4; ++j) {
            float4 v = *(const float4*)&Wb[1][idxAB(y0 + j, k)];
            b4[j][0] = v.x; b4[j][1] = v.y; b4[j][2] = v.z; b4[j][3] = v.w;
        }
        #pragma unroll
        for (int i = 0; i < 4; ++i)
            #pragma unroll
            for (int j = 0; j < 4; ++j)
                #pragma unroll
                for (int kk = 0; kk < 4; ++kk)
                    Cm[i][j] = fmaf(a4[i][kk], b4[j][kk], Cm[i][j]);
    }
    __syncthreads();

    // ---- initial W = Wg into Wb[0] (EW swizzle) ----
    #pragma unroll
    for (int k = 0; k < 16; ++k) {
        int idx = t + (k << 8);
        Wb[0][idxEW(idx >> 6, idx & 63)] = Wg[idx];
    }
    __syncthreads();

    float* Wcur  = Wb[0];
    float* Wnext = Wb[1];

    for (int cyc = 0; cyc < 10; ++cyc) {
        // e = s - C ; wn = e .* Rs   (registers)
        #pragma unroll
        for (int i = 0; i < 4; ++i)
            #pragma unroll
            for (int j = 0; j < 4; ++j) {
                e[i][j]  = s[i][j] - Cm[i][j];
                wn[i][j] = e[i][j] * Rs[i][j];
            }
        // publish e and W_next
        #pragma unroll
        for (int i = 0; i < 4; ++i) {
            float4 ev = {e[i][0], e[i][1], e[i][2], e[i][3]};
            float4 wv = {wn[i][0], wn[i][1], wn[i][2], wn[i][3]};
            *(float4*)&Eb[idxEW(x0 + i, y0)]    = ev;
            *(float4*)&Wnext[idxEW(x0 + i, y0)] = wv;
        }
        __syncthreads();

        // g[i][j] = sum_c Wcur[c][x0+i] * e[c][y0+j]
        float g[4][4];
        #pragma unroll
        for (int i = 0; i < 4; ++i)
            #pragma unroll
            for (int j = 0; j < 4; ++j) g[i][j] = 0.f;

        #pragma unroll
        for (int c = 0; c < 64; ++c) {
            float4 wv = *(const float4*)&Wcur[idxEW(c, x0)];
            float4 ev = *(const float4*)&Eb[idxEW(c, y0)];
            float w4[4] = {wv.x, wv.y, wv.z, wv.w};
            float e4[4] = {ev.x, ev.y, ev.z, ev.w};
            #pragma unroll
            for (int i = 0; i < 4; ++i)
                #pragma unroll
                for (int j = 0; j < 4; ++j)
                    g[i][j] = fmaf(w4[i], e4[j], g[i][j]);
        }

        // s += LR * (relu'(s) - e) .* g
        #pragma unroll
        for (int i = 0; i < 4; ++i)
            #pragma unroll
            for (int j = 0; j < 4; ++j) {
                float rp = s[i][j] > 0.f ? 1.f : 0.f;
                s[i][j] = fmaf(LRc * (rp - e[i][j]), g[i][j], s[i][j]);
            }

        float* tmp = Wcur; Wcur = Wnext; Wnext = tmp;
        __syncthreads();
    }

    // Wg_fin = wn of the 10th cycle (Wg is replaced, not accumulated)
    #pragma unroll
    for (int i = 0; i < 4; ++i) {
        float4 wv = {wn[i][0], wn[i][1], wn[i][2], wn[i][3]};
        *(float4*)(out + 4096 + (x0 + i) * 64 + y0) = wv;
    }
}

extern "C" void kernel_launch(void* const* d_in, const int* in_sizes, int n_in,
                              void* d_out, int out_size, void* d_ws, size_t ws_size,
                              hipStream_t stream) {
    const float* S   = (const float*)d_in[2];   // (15,64,64)
    const float* Wk  = (const float*)d_in[4];   // (14,64,64)
    const float* Wg  = (const float*)d_in[5];   // (64,64)
    float* out = (float*)d_out;                 // 8192 floats
    pcn_kernel<<<2, 256, 0, stream>>>(S, Wk, Wg, out);
}

// Round 4
// 88.097 us; speedup vs baseline: 1.1378x; 1.1378x over previous
//
#include <hip/hip_runtime.h>

// PCN reduced recurrence (validated round 1, absmax 0.0). Only S[13], S[14],
// Wk[13], Wg matter; out = [initial S14 ; Wg after 10 cycles].
//
//   C  = relu(S14) @ Wk13^T          (constant)
//   Rs = 0.01 * (S14^T > 0)          (constant)
//   loop 10:  e = s - C ; g = W^T e ; W = e.*Rs ; s += 0.01*(relu'(s)-e).*g
//
// Round-2 changes (latency fix):
//  - __launch_bounds__(256,1): round 1 got capped at 92 VGPRs -> the unrolled
//    c-loop serialized into 64 LDS round-trips/iter (measured 43us).
//  - depth-3 software-pipelined c-loop: 3 reg buffers x 4 c-steps, 8
//    ds_read_b128 in flight, FMA overlaps LDS latency.
//  - 4-wide ext-vector FMA so clang emits v_pk_fma_f32 (dual-issue fp32);
//    halves the VALU-issue floor. Accumulation order over c unchanged.

typedef float f4v __attribute__((ext_vector_type(4)));

static constexpr float LRc = 0.01f;

__device__ __forceinline__ int idxEW(int r, int c) {
    // row-major 64x64, float4-granular XOR swizzle by (r & 15)
    return (r << 6) + ((((c >> 2) ^ (r & 15)) << 2) | (c & 3));
}
__device__ __forceinline__ int idxAB(int r, int c) {
    return (r << 6) + ((((c >> 2) ^ ((r >> 2) & 15)) << 2) | (c & 3));
}

__global__ __launch_bounds__(256, 1)
void pcn_kernel(const float* __restrict__ S,    // (15,64,64)
                const float* __restrict__ Wk,   // (14,64,64)
                const float* __restrict__ Wg,   // (64,64)
                float* __restrict__ out)        // 8192 floats
{
    if (blockIdx.x == 1) {
        // out[0:4096] = S[14] (never updated by the reference)
        const float4* src = (const float4*)(S + 14 * 4096);
        float4* dst = (float4*)out;
        #pragma unroll
        for (int k = 0; k < 4; ++k)
            dst[threadIdx.x + (k << 8)] = src[threadIdx.x + (k << 8)];
        return;
    }

    __shared__ float Eb[2][4096];
    __shared__ float Wb[2][4096];

    const int t  = threadIdx.x;
    const int tx = t & 15, ty = t >> 4;
    const int x0 = tx << 2, y0 = ty << 2;

    const float* S13  = S  + 13 * 4096;
    const float* S14  = S  + 14 * 4096;
    const float* Wk13 = Wk + 13 * 4096;

    // ---- stage A=relu(S14)->Eb[0], B=Wk13->Eb[1] (AB swz); Wg->Wb[0] (EW swz)
    #pragma unroll
    for (int k = 0; k < 4; ++k) {
        int b4 = t + (k << 8);              // float4 index 0..1023
        int r = b4 >> 4, c = (b4 & 15) << 2;
        f4v a  = *(const f4v*)(S14  + (b4 << 2));
        f4v bb = *(const f4v*)(Wk13 + (b4 << 2));
        f4v w  = *(const f4v*)(Wg   + (b4 << 2));
        f4v ar = {fmaxf(a[0], 0.f), fmaxf(a[1], 0.f),
                  fmaxf(a[2], 0.f), fmaxf(a[3], 0.f)};
        *(f4v*)&Eb[0][idxAB(r, c)] = ar;
        *(f4v*)&Eb[1][idxAB(r, c)] = bb;
        *(f4v*)&Wb[0][idxEW(r, c)] = w;
    }

    float s[4][4], Rs[4][4];
    #pragma unroll
    for (int i = 0; i < 4; ++i) {
        f4v v = *(const f4v*)(S13 + (x0 + i) * 64 + y0);
        s[i][0] = v[0]; s[i][1] = v[1]; s[i][2] = v[2]; s[i][3] = v[3];
    }
    #pragma unroll
    for (int j = 0; j < 4; ++j) {
        f4v v = *(const f4v*)(S14 + (y0 + j) * 64 + x0);
        Rs[0][j] = v[0] > 0.f ? LRc : 0.f;
        Rs[1][j] = v[1] > 0.f ? LRc : 0.f;
        Rs[2][j] = v[2] > 0.f ? LRc : 0.f;
        Rs[3][j] = v[3] > 0.f ? LRc : 0.f;
    }
    __syncthreads();

    // ---- Cm[i][j] = sum_k A[x0+i][k] * B[y0+j][k], 4-lane split accumulators
    f4v ca[4][4];
    #pragma unroll
    for (int i = 0; i < 4; ++i)
        #pragma unroll
        for (int j = 0; j < 4; ++j) ca[i][j] = (f4v){0.f, 0.f, 0.f, 0.f};

    #pragma unroll
    for (int k = 0; k < 64; k += 4) {
        f4v av[4], bv[4];
        #pragma unroll
        for (int i = 0; i < 4; ++i) av[i] = *(const f4v*)&Eb[0][idxAB(x0 + i, k)];
        #pragma unroll
        for (int j = 0; j < 4; ++j) bv[j] = *(const f4v*)&Eb[1][idxAB(y0 + j, k)];
        #pragma unroll
        for (int i = 0; i < 4; ++i)
            #pragma unroll
            for (int j = 0; j < 4; ++j)
                ca[i][j] += av[i] * bv[j];
    }
    float Cm[4][4];
    #pragma unroll
    for (int i = 0; i < 4; ++i)
        #pragma unroll
        for (int j = 0; j < 4; ++j)
            Cm[i][j] = (ca[i][j][0] + ca[i][j][1]) + (ca[i][j][2] + ca[i][j][3]);
    __syncthreads();

    float e[4][4], wn[4][4];

    for (int cyc = 0; cyc < 10; ++cyc) {
        float* Ecur = Eb[cyc & 1];
        float* Wcur = Wb[cyc & 1];
        float* Wnxt = Wb[(cyc & 1) ^ 1];

        // e = s - C ; wn = e .* Rs  (registers), publish to LDS
        #pragma unroll
        for (int i = 0; i < 4; ++i) {
            #pragma unroll
            for (int j = 0; j < 4; ++j) {
                e[i][j]  = s[i][j] - Cm[i][j];
                wn[i][j] = e[i][j] * Rs[i][j];
            }
            f4v ev = {e[i][0], e[i][1], e[i][2], e[i][3]};
            f4v wv_ = {wn[i][0], wn[i][1], wn[i][2], wn[i][3]};
            *(f4v*)&Ecur[idxEW(x0 + i, y0)] = ev;
            *(f4v*)&Wnxt[idxEW(x0 + i, y0)] = wv_;
        }
        __syncthreads();

        // g[i][:] = sum_c Wcur[c][x0+i] * e[c][y0:y0+4]
        // depth-3 pipelined over 16 groups of 4 c-steps
        f4v gg[4];
        #pragma unroll
        for (int i = 0; i < 4; ++i) gg[i] = (f4v){0.f, 0.f, 0.f, 0.f};

        f4v wv[3][4], ev[3][4];
        #pragma unroll
        for (int q = 0; q < 4; ++q) {
            wv[0][q] = *(const f4v*)&Wcur[idxEW(q, x0)];
            ev[0][q] = *(const f4v*)&Ecur[idxEW(q, y0)];
        }
        #pragma unroll
        for (int q = 0; q < 4; ++q) {
            wv[1][q] = *(const f4v*)&Wcur[idxEW(4 + q, x0)];
            ev[1][q] = *(const f4v*)&Ecur[idxEW(4 + q, y0)];
        }
        #pragma unroll
        for (int gb = 0; gb < 16; ++gb) {
            if (gb < 14) {
                const int c0 = (gb + 2) << 2;
                const int bi = (gb + 2) % 3;
                #pragma unroll
                for (int q = 0; q < 4; ++q) {
                    wv[bi][q] = *(const f4v*)&Wcur[idxEW(c0 + q, x0)];
                    ev[bi][q] = *(const f4v*)&Ecur[idxEW(c0 + q, y0)];
                }
            }
            const int bi = gb % 3;
            #pragma unroll
            for (int q = 0; q < 4; ++q) {
                f4v w4 = wv[bi][q], e4 = ev[bi][q];
                #pragma unroll
                for (int i = 0; i < 4; ++i) {
                    f4v ws = {w4[i], w4[i], w4[i], w4[i]};
                    gg[i] += ws * e4;          // -> v_pk_fma_f32 pairs
                }
            }
        }

        // s += LR * (relu'(s) - e) .* g
        #pragma unroll
        for (int i = 0; i < 4; ++i)
            #pragma unroll
            for (int j = 0; j < 4; ++j) {
                float rp = s[i][j] > 0.f ? 1.f : 0.f;
                s[i][j] = fmaf(LRc * (rp - e[i][j]), gg[i][j], s[i][j]);
            }
        __syncthreads();
    }

    // Wg_fin = wn of the 10th cycle (Wg is replaced each cycle)
    #pragma unroll
    for (int i = 0; i < 4; ++i) {
        float4 wv_ = {wn[i][0], wn[i][1], wn[i][2], wn[i][3]};
        *(float4*)(out + 4096 + (x0 + i) * 64 + y0) = wv_;
    }
}

extern "C" void kernel_launch(void* const* d_in, const int* in_sizes, int n_in,
                              void* d_out, int out_size, void* d_ws, size_t ws_size,
                              hipStream_t stream) {
    const float* S  = (const float*)d_in[2];   // (15,64,64)
    const float* Wk = (const float*)d_in[4];   // (14,64,64)
    const float* Wg = (const float*)d_in[5];   // (64,64)
    float* out = (float*)d_out;                // 8192 floats
    pcn_kernel<<<2, 256, 0, stream>>>(S, Wk, Wg, out);
}

// Round 5
// 75.780 us; speedup vs baseline: 1.3227x; 1.1625x over previous
//
#include <hip/hip_runtime.h>

// PCN reduced recurrence (math validated R1, absmax 0.0). Only S[13], S[14],
// Wk[13], Wg matter; out = [initial S14 ; Wg after 10 cycles].
//
//   C  = relu(S14) @ Wk13^T          (constant)   [3-term split-bf16 MFMA]
//   Rs = 0.01 * (S14^T > 0)          (constant)
//   loop 10:  e = s - C ; g = W^T e  [2-term split-bf16 MFMA]
//             W = e.*Rs ; s += 0.01*(relu'(s)-e).*g
//
// R5 structure: everything lives in the mfma_f32_16x16x32_bf16 C/D fragment
// layout (col = lane&15, row = 4*(lane>>4)+reg — HW-verified mapping), so
// e/W/s/g updates are register-local and g from MFMA aligns 1:1 with s.
// Per iter, operands cross through LDS once: packed {hi x4, lo x4} 16B quads,
// XOR-swizzled (quad ^ row&15) for bank balance; double-buffered -> one
// __syncthreads per iteration. R4 post-mortem: fp32 c-loop was LDS-throughput
// bound (512 b128/iter ~ 6.1K cy); this is 112 b128/iter + 24 MFMA/wave.

typedef float  f32x4  __attribute__((ext_vector_type(4)));
typedef short  bf16x8 __attribute__((ext_vector_type(8)));

static constexpr float LRc = 0.01f;

union Frag { int i[4]; bf16x8 v; };

__device__ __forceinline__ unsigned hi16(float x) {
    return __float_as_uint(x) & 0xFFFF0000u;
}
__device__ __forceinline__ int pk2(unsigned ha, unsigned hb) {
    return (int)((ha >> 16) | hb);   // a -> low bf16, b -> high bf16
}

// 2-term split of 4 consecutive c-values -> one 16B quad {h01, h23, l01, l23}
__device__ __forceinline__ int4 split2pack(float v0, float v1, float v2, float v3) {
    unsigned h0 = hi16(v0), h1 = hi16(v1), h2 = hi16(v2), h3 = hi16(v3);
    float r0 = v0 - __uint_as_float(h0);
    float r1 = v1 - __uint_as_float(h1);
    float r2 = v2 - __uint_as_float(h2);
    float r3 = v3 - __uint_as_float(h3);
    return make_int4(pk2(h0, h1), pk2(h2, h3),
                     pk2(hi16(r0), hi16(r1)), pk2(hi16(r2), hi16(r3)));
}

// 3-term split of 8 consecutive k-values into three bf16x8 fragments
__device__ __forceinline__ void split3pack8(const float v[8],
                                            bf16x8& H, bf16x8& M, bf16x8& L) {
    Frag fh, fm, fl;
    #pragma unroll
    for (int p = 0; p < 4; ++p) {
        unsigned ha = hi16(v[2*p]),   hb = hi16(v[2*p+1]);
        float ra = v[2*p]   - __uint_as_float(ha);
        float rb = v[2*p+1] - __uint_as_float(hb);
        unsigned ma = hi16(ra), mb = hi16(rb);
        float sa = ra - __uint_as_float(ma);
        float sb = rb - __uint_as_float(mb);
        fh.i[p] = pk2(ha, hb);
        fm.i[p] = pk2(ma, mb);
        fl.i[p] = pk2(hi16(sa), hi16(sb));
    }
    H = fh.v; M = fm.v; L = fl.v;
}

__device__ __forceinline__ bf16x8 mkfrag(int a, int b, int c, int d) {
    Frag f; f.i[0] = a; f.i[1] = b; f.i[2] = c; f.i[3] = d; return f.v;
}

#define MFMA __builtin_amdgcn_mfma_f32_16x16x32_bf16

__global__ __launch_bounds__(256, 1)
void pcn_kernel(const float* __restrict__ S,    // (15,64,64)
                const float* __restrict__ Wk,   // (14,64,64)
                const float* __restrict__ Wg,   // (64,64)
                float* __restrict__ out)        // 8192 floats
{
    if (blockIdx.x == 1) {
        // out[0:4096] = S[14] (never updated by the reference)
        const float4* src = (const float4*)(S + 14 * 4096);
        float4* dst = (float4*)out;
        #pragma unroll
        for (int k = 0; k < 4; ++k)
            dst[threadIdx.x + (k << 8)] = src[threadIdx.x + (k << 8)];
        return;
    }

    // packed operand tiles: [buf][row][quad], quad = 16B {hi x4, lo x4}
    __shared__ int4 Apk[2][64][16];   // A = W^T  (A[x][c] = W[c][x])
    __shared__ int4 Bpk[2][64][16];   // B = e    (B[c][y])

    const int t  = threadIdx.x;
    const int l  = t & 63;
    const int w  = t >> 6;        // wave 0..3 -> owns output cols 16w..16w+15
    const int rg = l >> 4;        // lane row-group 0..3
    const int cl = l & 15;        // lane col within tile
    const int Y  = (w << 4) + cl; // this lane's global column

    const float* S13  = S  + 13 * 4096;
    const float* S14  = S  + 14 * 4096;
    const float* Wk13 = Wk + 13 * 4096;

    // ---------- C = relu(S14) @ Wk13^T via 3-term split MFMA (once) --------
    // B-operand: B[k][Y] = Wk13[Y][k]  (row Y of Wk13, contiguous in k)
    bf16x8 cbh[2], cbm[2], cbl[2];
    #pragma unroll
    for (int kc = 0; kc < 2; ++kc) {
        const float* p = Wk13 + Y * 64 + kc * 32 + rg * 8;
        float4 q0 = *(const float4*)p;
        float4 q1 = *(const float4*)(p + 4);
        float v[8] = {q0.x, q0.y, q0.z, q0.w, q1.x, q1.y, q1.z, q1.w};
        split3pack8(v, cbh[kc], cbm[kc], cbl[kc]);
    }

    f32x4 Cacc[4];
    #pragma unroll
    for (int m = 0; m < 4; ++m) Cacc[m] = (f32x4){0.f, 0.f, 0.f, 0.f};

    #pragma unroll
    for (int m = 0; m < 4; ++m) {
        #pragma unroll
        for (int kc = 0; kc < 2; ++kc) {
            // A-operand: A[x][k] = relu(S14[x][k]), x = 16m + cl
            const float* p = S14 + ((m << 4) + cl) * 64 + kc * 32 + rg * 8;
            float4 q0 = *(const float4*)p;
            float4 q1 = *(const float4*)(p + 4);
            float v[8] = {fmaxf(q0.x, 0.f), fmaxf(q0.y, 0.f),
                          fmaxf(q0.z, 0.f), fmaxf(q0.w, 0.f),
                          fmaxf(q1.x, 0.f), fmaxf(q1.y, 0.f),
                          fmaxf(q1.z, 0.f), fmaxf(q1.w, 0.f)};
            bf16x8 ah, am, al;
            split3pack8(v, ah, am, al);
            // products down to 2^-24: hh, hm, mh, mm, hl, lh
            Cacc[m] = MFMA(ah, cbh[kc], Cacc[m], 0, 0, 0);
            Cacc[m] = MFMA(ah, cbm[kc], Cacc[m], 0, 0, 0);
            Cacc[m] = MFMA(am, cbh[kc], Cacc[m], 0, 0, 0);
            Cacc[m] = MFMA(am, cbm[kc], Cacc[m], 0, 0, 0);
            Cacc[m] = MFMA(ah, cbl[kc], Cacc[m], 0, 0, 0);
            Cacc[m] = MFMA(al, cbh[kc], Cacc[m], 0, 0, 0);
        }
    }

    // ---------- register state in fragment layout: (X = 16m+4rg+r, Y) ------
    float s[4][4], Rs[4][4], Wc[4][4];
    #pragma unroll
    for (int m = 0; m < 4; ++m) {
        #pragma unroll
        for (int r = 0; r < 4; ++r) {
            const int X = (m << 4) + (rg << 2) + r;
            s[m][r]  = S13[X * 64 + Y];
            Wc[m][r] = Wg[X * 64 + Y];
        }
        // Rs[m][r] = LR * (S14[Y][X] > 0)
        float4 q = *(const float4*)(S14 + Y * 64 + (m << 4) + (rg << 2));
        Rs[m][0] = q.x > 0.f ? LRc : 0.f;
        Rs[m][1] = q.y > 0.f ? LRc : 0.f;
        Rs[m][2] = q.z > 0.f ? LRc : 0.f;
        Rs[m][3] = q.w > 0.f ? LRc : 0.f;
    }

    // ---------- 10 cycles ----------
    float e[4][4], wn[4][4];
    for (int it = 0; it < 10; ++it) {
        const int buf = it & 1;

        // e = s - C ; wn = e .* Rs ; stage W_t (transposed) and e_t into LDS.
        // Lane owns (X = 16m+4rg+r, Y): A[x][c] = W[c][x] -> write row Y,
        // c-block 16m+4rg (4 contiguous c = this lane's r's). Same for B(e).
        #pragma unroll
        for (int m = 0; m < 4; ++m) {
            #pragma unroll
            for (int r = 0; r < 4; ++r) {
                e[m][r]  = s[m][r] - Cacc[m][r];
                wn[m][r] = e[m][r] * Rs[m][r];
            }
            const int qw = ((m << 2) + rg) ^ cl;   // 16B-granular XOR swizzle
            Apk[buf][Y][qw] = split2pack(Wc[m][0], Wc[m][1], Wc[m][2], Wc[m][3]);
            Bpk[buf][Y][qw] = split2pack(e[m][0],  e[m][1],  e[m][2],  e[m][3]);
        }
        __syncthreads();

        // g = A*B, A-frag row = 16m+cl, k = 32kc+8rg+j ; B-frag row(col) = Y
        f32x4 g[4];
        #pragma unroll
        for (int m = 0; m < 4; ++m) g[m] = (f32x4){0.f, 0.f, 0.f, 0.f};

        #pragma unroll
        for (int kc = 0; kc < 2; ++kc) {
            const int q0 = (kc << 3) + (rg << 1);
            int4 b0 = Bpk[buf][Y][q0 ^ cl];
            int4 b1 = Bpk[buf][Y][(q0 + 1) ^ cl];
            bf16x8 bh = mkfrag(b0.x, b0.y, b1.x, b1.y);
            bf16x8 bl = mkfrag(b0.z, b0.w, b1.z, b1.w);
            #pragma unroll
            for (int m = 0; m < 4; ++m) {
                int4 a0 = Apk[buf][(m << 4) + cl][q0 ^ cl];
                int4 a1 = Apk[buf][(m << 4) + cl][(q0 + 1) ^ cl];
                bf16x8 ah = mkfrag(a0.x, a0.y, a1.x, a1.y);
                bf16x8 al = mkfrag(a0.z, a0.w, a1.z, a1.w);
                g[m] = MFMA(ah, bh, g[m], 0, 0, 0);   // hh
                g[m] = MFMA(ah, bl, g[m], 0, 0, 0);   // hl
                g[m] = MFMA(al, bh, g[m], 0, 0, 0);   // lh
            }
        }

        // s += LR * (relu'(s) - e) .* g ; W_{t+1} = wn
        #pragma unroll
        for (int m = 0; m < 4; ++m)
            #pragma unroll
            for (int r = 0; r < 4; ++r) {
                float rp = s[m][r] > 0.f ? 1.f : 0.f;
                s[m][r] = fmaf(LRc * (rp - e[m][r]), g[m][r], s[m][r]);
                Wc[m][r] = wn[m][r];
            }
        // no 2nd barrier: double-buffered; next iter writes buf^1, and the
        // barrier at iter t+1 orders R(buf) before W(buf) at iter t+2.
    }

    // out[4096:8192] = W after 10 cycles (= wn of the last iter)
    #pragma unroll
    for (int m = 0; m < 4; ++m)
        #pragma unroll
        for (int r = 0; r < 4; ++r)
            out[4096 + ((m << 4) + (rg << 2) + r) * 64 + Y] = wn[m][r];
}

extern "C" void kernel_launch(void* const* d_in, const int* in_sizes, int n_in,
                              void* d_out, int out_size, void* d_ws, size_t ws_size,
                              hipStream_t stream) {
    const float* S  = (const float*)d_in[2];   // (15,64,64)
    const float* Wk = (const float*)d_in[4];   // (14,64,64)
    const float* Wg = (const float*)d_in[5];   // (64,64)
    float* out = (float*)d_out;                // 8192 floats
    pcn_kernel<<<2, 256, 0, stream>>>(S, Wk, Wg, out);
}

// Round 6
// 74.206 us; speedup vs baseline: 1.3507x; 1.0212x over previous
//
#include <hip/hip_runtime.h>

// PCN reduced recurrence (math validated R1/R5, absmax 0.0). Only S[13],
// S[14], Wk[13], Wg matter; out = [initial S14 ; Wg after 10 cycles].
//
//   C  = relu(S14) @ Wk13^T          (constant)   [3-term split-bf16 MFMA]
//   Rs = 0.01 * (S14^T > 0)          (constant)
//   loop 10:  e = s - C ; g = W^T e  [2-term split-bf16 MFMA]
//             W = e.*Rs ; s += 0.01*(relu'(s)-e).*g
//
// R6 change (dep-stall fix; R5 measured ~19us kernel vs ~9 ideal):
//  R5's g-loop interleaved ds_read pairs with their MFMAs -> 8 serialized
//  LDS round-trips (~250cy each) per iteration with 1 wave/SIMD. Now ALL
//  20 ds_read_b128 issue as one burst (single lgkmcnt wait), pinned with
//  sched_barrier(0), then the 24-MFMA chain runs. Per-accumulator FP order
//  unchanged -> bit-identical result. Also: s/Rs/Wc global loads hoisted
//  above the C-precompute to overlap their latency with split-pack VALU.

typedef float  f32x4  __attribute__((ext_vector_type(4)));
typedef short  bf16x8 __attribute__((ext_vector_type(8)));

static constexpr float LRc = 0.01f;

union Frag { int i[4]; bf16x8 v; };

__device__ __forceinline__ unsigned hi16(float x) {
    return __float_as_uint(x) & 0xFFFF0000u;
}
__device__ __forceinline__ int pk2(unsigned ha, unsigned hb) {
    return (int)((ha >> 16) | hb);   // a -> low bf16, b -> high bf16
}

// 2-term split of 4 consecutive c-values -> one 16B quad {h01, h23, l01, l23}
__device__ __forceinline__ int4 split2pack(float v0, float v1, float v2, float v3) {
    unsigned h0 = hi16(v0), h1 = hi16(v1), h2 = hi16(v2), h3 = hi16(v3);
    float r0 = v0 - __uint_as_float(h0);
    float r1 = v1 - __uint_as_float(h1);
    float r2 = v2 - __uint_as_float(h2);
    float r3 = v3 - __uint_as_float(h3);
    return make_int4(pk2(h0, h1), pk2(h2, h3),
                     pk2(hi16(r0), hi16(r1)), pk2(hi16(r2), hi16(r3)));
}

// 3-term split of 8 consecutive k-values into three bf16x8 fragments
__device__ __forceinline__ void split3pack8(const float v[8],
                                            bf16x8& H, bf16x8& M, bf16x8& L) {
    Frag fh, fm, fl;
    #pragma unroll
    for (int p = 0; p < 4; ++p) {
        unsigned ha = hi16(v[2*p]),   hb = hi16(v[2*p+1]);
        float ra = v[2*p]   - __uint_as_float(ha);
        float rb = v[2*p+1] - __uint_as_float(hb);
        unsigned ma = hi16(ra), mb = hi16(rb);
        float sa = ra - __uint_as_float(ma);
        float sb = rb - __uint_as_float(mb);
        fh.i[p] = pk2(ha, hb);
        fm.i[p] = pk2(ma, mb);
        fl.i[p] = pk2(hi16(sa), hi16(sb));
    }
    H = fh.v; M = fm.v; L = fl.v;
}

__device__ __forceinline__ bf16x8 mkfrag(int a, int b, int c, int d) {
    Frag f; f.i[0] = a; f.i[1] = b; f.i[2] = c; f.i[3] = d; return f.v;
}

#define MFMA __builtin_amdgcn_mfma_f32_16x16x32_bf16

__global__ __launch_bounds__(256, 1)
void pcn_kernel(const float* __restrict__ S,    // (15,64,64)
                const float* __restrict__ Wk,   // (14,64,64)
                const float* __restrict__ Wg,   // (64,64)
                float* __restrict__ out)        // 8192 floats
{
    if (blockIdx.x == 1) {
        // out[0:4096] = S[14] (never updated by the reference)
        const float4* src = (const float4*)(S + 14 * 4096);
        float4* dst = (float4*)out;
        #pragma unroll
        for (int k = 0; k < 4; ++k)
            dst[threadIdx.x + (k << 8)] = src[threadIdx.x + (k << 8)];
        return;
    }

    // packed operand tiles: [buf][row][quad], quad = 16B {hi x4, lo x4}
    __shared__ int4 Apk[2][64][16];   // A = W^T  (A[x][c] = W[c][x])
    __shared__ int4 Bpk[2][64][16];   // B = e    (B[c][y])

    const int t  = threadIdx.x;
    const int l  = t & 63;
    const int w  = t >> 6;        // wave 0..3 -> owns output cols 16w..16w+15
    const int rg = l >> 4;        // lane row-group 0..3
    const int cl = l & 15;        // lane col within tile
    const int Y  = (w << 4) + cl; // this lane's global column

    const float* S13  = S  + 13 * 4096;
    const float* S14  = S  + 14 * 4096;
    const float* Wk13 = Wk + 13 * 4096;

    // ---------- register state loads FIRST (latency overlaps C-precompute)
    float s[4][4], Rs[4][4], Wc[4][4];
    #pragma unroll
    for (int m = 0; m < 4; ++m) {
        #pragma unroll
        for (int r = 0; r < 4; ++r) {
            const int X = (m << 4) + (rg << 2) + r;
            s[m][r]  = S13[X * 64 + Y];
            Wc[m][r] = Wg[X * 64 + Y];
        }
        // Rs[m][r] = LR * (S14[Y][X] > 0)
        float4 q = *(const float4*)(S14 + Y * 64 + (m << 4) + (rg << 2));
        Rs[m][0] = q.x > 0.f ? LRc : 0.f;
        Rs[m][1] = q.y > 0.f ? LRc : 0.f;
        Rs[m][2] = q.z > 0.f ? LRc : 0.f;
        Rs[m][3] = q.w > 0.f ? LRc : 0.f;
    }

    // ---------- C = relu(S14) @ Wk13^T via 3-term split MFMA (once) --------
    // B-operand: B[k][Y] = Wk13[Y][k]  (row Y of Wk13, contiguous in k)
    bf16x8 cbh[2], cbm[2], cbl[2];
    #pragma unroll
    for (int kc = 0; kc < 2; ++kc) {
        const float* p = Wk13 + Y * 64 + kc * 32 + rg * 8;
        float4 q0 = *(const float4*)p;
        float4 q1 = *(const float4*)(p + 4);
        float v[8] = {q0.x, q0.y, q0.z, q0.w, q1.x, q1.y, q1.z, q1.w};
        split3pack8(v, cbh[kc], cbm[kc], cbl[kc]);
    }

    f32x4 Cacc[4];
    #pragma unroll
    for (int m = 0; m < 4; ++m) Cacc[m] = (f32x4){0.f, 0.f, 0.f, 0.f};

    #pragma unroll
    for (int m = 0; m < 4; ++m) {
        #pragma unroll
        for (int kc = 0; kc < 2; ++kc) {
            // A-operand: A[x][k] = relu(S14[x][k]), x = 16m + cl
            const float* p = S14 + ((m << 4) + cl) * 64 + kc * 32 + rg * 8;
            float4 q0 = *(const float4*)p;
            float4 q1 = *(const float4*)(p + 4);
            float v[8] = {fmaxf(q0.x, 0.f), fmaxf(q0.y, 0.f),
                          fmaxf(q0.z, 0.f), fmaxf(q0.w, 0.f),
                          fmaxf(q1.x, 0.f), fmaxf(q1.y, 0.f),
                          fmaxf(q1.z, 0.f), fmaxf(q1.w, 0.f)};
            bf16x8 ah, am, al;
            split3pack8(v, ah, am, al);
            // products down to 2^-24: hh, hm, mh, mm, hl, lh
            Cacc[m] = MFMA(ah, cbh[kc], Cacc[m], 0, 0, 0);
            Cacc[m] = MFMA(ah, cbm[kc], Cacc[m], 0, 0, 0);
            Cacc[m] = MFMA(am, cbh[kc], Cacc[m], 0, 0, 0);
            Cacc[m] = MFMA(am, cbm[kc], Cacc[m], 0, 0, 0);
            Cacc[m] = MFMA(ah, cbl[kc], Cacc[m], 0, 0, 0);
            Cacc[m] = MFMA(al, cbh[kc], Cacc[m], 0, 0, 0);
        }
    }

    // ---------- 10 cycles ----------
    float e[4][4], wn[4][4];
    for (int it = 0; it < 10; ++it) {
        const int buf = it & 1;

        // e = s - C ; wn = e .* Rs ; stage W_t (transposed) and e_t into LDS.
        // Lane owns (X = 16m+4rg+r, Y): A[x][c] = W[c][x] -> write row Y,
        // c-quad = (m<<2)+rg (4 contiguous c = this lane's r's). Same for B(e).
        #pragma unroll
        for (int m = 0; m < 4; ++m) {
            #pragma unroll
            for (int r = 0; r < 4; ++r) {
                e[m][r]  = s[m][r] - Cacc[m][r];
                wn[m][r] = e[m][r] * Rs[m][r];
            }
            const int qw = ((m << 2) + rg) ^ cl;   // 16B-granular XOR swizzle
            Apk[buf][Y][qw] = split2pack(Wc[m][0], Wc[m][1], Wc[m][2], Wc[m][3]);
            Bpk[buf][Y][qw] = split2pack(e[m][0],  e[m][1],  e[m][2],  e[m][3]);
        }
        __syncthreads();

        // -------- batched read burst: ALL 20 ds_read_b128, one wait-point
        int4 br[2][2], arr[2][4][2];
        #pragma unroll
        for (int kc = 0; kc < 2; ++kc) {
            const int q0 = (kc << 3) + (rg << 1);
            br[kc][0] = Bpk[buf][Y][q0 ^ cl];
            br[kc][1] = Bpk[buf][Y][(q0 + 1) ^ cl];
            #pragma unroll
            for (int m = 0; m < 4; ++m) {
                arr[kc][m][0] = Apk[buf][(m << 4) + cl][q0 ^ cl];
                arr[kc][m][1] = Apk[buf][(m << 4) + cl][(q0 + 1) ^ cl];
            }
        }
        __builtin_amdgcn_sched_barrier(0);   // pin: reads above, MFMAs below

        // -------- MFMA chain (per-acc order identical to R5: kc0 hh,hl,lh;
        // kc1 hh,hl,lh -> bit-identical numerics)
        f32x4 g[4];
        #pragma unroll
        for (int m = 0; m < 4; ++m) g[m] = (f32x4){0.f, 0.f, 0.f, 0.f};

        #pragma unroll
        for (int kc = 0; kc < 2; ++kc) {
            bf16x8 bh = mkfrag(br[kc][0].x, br[kc][0].y, br[kc][1].x, br[kc][1].y);
            bf16x8 bl = mkfrag(br[kc][0].z, br[kc][0].w, br[kc][1].z, br[kc][1].w);
            #pragma unroll
            for (int m = 0; m < 4; ++m) {
                bf16x8 ah = mkfrag(arr[kc][m][0].x, arr[kc][m][0].y,
                                   arr[kc][m][1].x, arr[kc][m][1].y);
                bf16x8 al = mkfrag(arr[kc][m][0].z, arr[kc][m][0].w,
                                   arr[kc][m][1].z, arr[kc][m][1].w);
                g[m] = MFMA(ah, bh, g[m], 0, 0, 0);   // hh
                g[m] = MFMA(ah, bl, g[m], 0, 0, 0);   // hl
                g[m] = MFMA(al, bh, g[m], 0, 0, 0);   // lh
            }
        }

        // s += LR * (relu'(s) - e) .* g ; W_{t+1} = wn
        #pragma unroll
        for (int m = 0; m < 4; ++m)
            #pragma unroll
            for (int r = 0; r < 4; ++r) {
                float rp = s[m][r] > 0.f ? 1.f : 0.f;
                s[m][r] = fmaf(LRc * (rp - e[m][r]), g[m][r], s[m][r]);
                Wc[m][r] = wn[m][r];
            }
        // no 2nd barrier: double-buffered; next iter writes buf^1, and the
        // barrier at iter t+1 orders R(buf) before W(buf) at iter t+2.
    }

    // out[4096:8192] = W after 10 cycles (= wn of the last iter)
    #pragma unroll
    for (int m = 0; m < 4; ++m)
        #pragma unroll
        for (int r = 0; r < 4; ++r)
            out[4096 + ((m << 4) + (rg << 2) + r) * 64 + Y] = wn[m][r];
}

extern "C" void kernel_launch(void* const* d_in, const int* in_sizes, int n_in,
                              void* d_out, int out_size, void* d_ws, size_t ws_size,
                              hipStream_t stream) {
    const float* S  = (const float*)d_in[2];   // (15,64,64)
    const float* Wk = (const float*)d_in[4];   // (14,64,64)
    const float* Wg = (const float*)d_in[5];   // (64,64)
    float* out = (float*)d_out;                // 8192 floats
    pcn_kernel<<<2, 256, 0, stream>>>(S, Wk, Wg, out);
}

// Round 7
// 72.508 us; speedup vs baseline: 1.3824x; 1.0234x over previous
//
#include <hip/hip_runtime.h>

// PCN reduced recurrence (math validated R1/R5/R6, absmax 0.0). Only S[13],
// S[14], Wk[13], Wg matter; out = [initial S14 ; Wg after 10 cycles].
//
//   C  = relu(S14) @ Wk13^T          (constant)   [3-term split-bf16 MFMA]
//   Rs = 0.01 * (S14^T > 0)          (constant)
//   loop 10:  e = s - C ; g = W^T e  [2-term split-bf16 MFMA]
//             W = e.*Rs ; s += 0.01*(relu'(s)-e).*g
//
// R7 change (TLP fix; R6's read-batching was NEUTRAL -> not issue-order
// bound): 4 waves = 1 wave/SIMD left every barrier/lgkmcnt/MFMA-chain stall
// exposed. Now 8 waves (512 thr, 2/SIMD): wave w owns column-group (w&3) and
// m-half (w>>2). CU-wide LDS traffic ~flat (128 vs 112 b128/iter) but each
// SIMD's second wave covers the other's stalls; setup cold-loads and MFMA
// chains (24/wave, was 48) also overlap. Per-accumulator FP order unchanged
// -> absmax must stay 0.0.

typedef float  f32x4  __attribute__((ext_vector_type(4)));
typedef short  bf16x8 __attribute__((ext_vector_type(8)));

static constexpr float LRc = 0.01f;

union Frag { int i[4]; bf16x8 v; };

__device__ __forceinline__ unsigned hi16(float x) {
    return __float_as_uint(x) & 0xFFFF0000u;
}
__device__ __forceinline__ int pk2(unsigned ha, unsigned hb) {
    return (int)((ha >> 16) | hb);   // a -> low bf16, b -> high bf16
}

// 2-term split of 4 consecutive c-values -> one 16B quad {h01, h23, l01, l23}
__device__ __forceinline__ int4 split2pack(float v0, float v1, float v2, float v3) {
    unsigned h0 = hi16(v0), h1 = hi16(v1), h2 = hi16(v2), h3 = hi16(v3);
    float r0 = v0 - __uint_as_float(h0);
    float r1 = v1 - __uint_as_float(h1);
    float r2 = v2 - __uint_as_float(h2);
    float r3 = v3 - __uint_as_float(h3);
    return make_int4(pk2(h0, h1), pk2(h2, h3),
                     pk2(hi16(r0), hi16(r1)), pk2(hi16(r2), hi16(r3)));
}

// 3-term split of 8 consecutive k-values into three bf16x8 fragments
__device__ __forceinline__ void split3pack8(const float v[8],
                                            bf16x8& H, bf16x8& M, bf16x8& L) {
    Frag fh, fm, fl;
    #pragma unroll
    for (int p = 0; p < 4; ++p) {
        unsigned ha = hi16(v[2*p]),   hb = hi16(v[2*p+1]);
        float ra = v[2*p]   - __uint_as_float(ha);
        float rb = v[2*p+1] - __uint_as_float(hb);
        unsigned ma = hi16(ra), mb = hi16(rb);
        float sa = ra - __uint_as_float(ma);
        float sb = rb - __uint_as_float(mb);
        fh.i[p] = pk2(ha, hb);
        fm.i[p] = pk2(ma, mb);
        fl.i[p] = pk2(hi16(sa), hi16(sb));
    }
    H = fh.v; M = fm.v; L = fl.v;
}

__device__ __forceinline__ bf16x8 mkfrag(int a, int b, int c, int d) {
    Frag f; f.i[0] = a; f.i[1] = b; f.i[2] = c; f.i[3] = d; return f.v;
}

#define MFMA __builtin_amdgcn_mfma_f32_16x16x32_bf16

__global__ __launch_bounds__(512, 2)
void pcn_kernel(const float* __restrict__ S,    // (15,64,64)
                const float* __restrict__ Wk,   // (14,64,64)
                const float* __restrict__ Wg,   // (64,64)
                float* __restrict__ out)        // 8192 floats
{
    if (blockIdx.x == 1) {
        // out[0:4096] = S[14] (never updated by the reference)
        const float4* src = (const float4*)(S + 14 * 4096);
        float4* dst = (float4*)out;
        #pragma unroll
        for (int k = 0; k < 2; ++k)
            dst[threadIdx.x + (k << 9)] = src[threadIdx.x + (k << 9)];
        return;
    }

    // packed operand tiles: [buf][row][quad], quad = 16B {hi x4, lo x4}
    __shared__ int4 Apk[2][64][16];   // A = W^T  (A[x][c] = W[c][x])
    __shared__ int4 Bpk[2][64][16];   // B = e    (B[c][y])

    const int t  = threadIdx.x;
    const int l  = t & 63;
    const int w  = t >> 6;        // wave 0..7
    const int cg = w & 3;         // column group: cols 16cg..16cg+15
    const int mh = w >> 2;        // m-half: this wave's m = 2*mh + mm
    const int rg = l >> 4;        // lane row-group 0..3
    const int cl = l & 15;        // lane col within tile
    const int Y  = (cg << 4) + cl;

    const float* S13  = S  + 13 * 4096;
    const float* S14  = S  + 14 * 4096;
    const float* Wk13 = Wk + 13 * 4096;

    // ---------- register state loads FIRST (latency overlaps C-precompute)
    float s[2][4], Rs[2][4], Wc[2][4];
    #pragma unroll
    for (int mm = 0; mm < 2; ++mm) {
        const int m = (mh << 1) + mm;
        #pragma unroll
        for (int r = 0; r < 4; ++r) {
            const int X = (m << 4) + (rg << 2) + r;
            s[mm][r]  = S13[X * 64 + Y];
            Wc[mm][r] = Wg[X * 64 + Y];
        }
        // Rs[mm][r] = LR * (S14[Y][X] > 0)
        float4 q = *(const float4*)(S14 + Y * 64 + (m << 4) + (rg << 2));
        Rs[mm][0] = q.x > 0.f ? LRc : 0.f;
        Rs[mm][1] = q.y > 0.f ? LRc : 0.f;
        Rs[mm][2] = q.z > 0.f ? LRc : 0.f;
        Rs[mm][3] = q.w > 0.f ? LRc : 0.f;
    }

    // ---------- C = relu(S14) @ Wk13^T via 3-term split MFMA (once) --------
    // B-operand: B[k][Y] = Wk13[Y][k]  (row Y of Wk13, contiguous in k)
    bf16x8 cbh[2], cbm[2], cbl[2];
    #pragma unroll
    for (int kc = 0; kc < 2; ++kc) {
        const float* p = Wk13 + Y * 64 + kc * 32 + rg * 8;
        float4 q0 = *(const float4*)p;
        float4 q1 = *(const float4*)(p + 4);
        float v[8] = {q0.x, q0.y, q0.z, q0.w, q1.x, q1.y, q1.z, q1.w};
        split3pack8(v, cbh[kc], cbm[kc], cbl[kc]);
    }

    f32x4 Cacc[2];
    #pragma unroll
    for (int mm = 0; mm < 2; ++mm) Cacc[mm] = (f32x4){0.f, 0.f, 0.f, 0.f};

    #pragma unroll
    for (int mm = 0; mm < 2; ++mm) {
        const int m = (mh << 1) + mm;
        #pragma unroll
        for (int kc = 0; kc < 2; ++kc) {
            // A-operand: A[x][k] = relu(S14[x][k]), x = 16m + cl
            const float* p = S14 + ((m << 4) + cl) * 64 + kc * 32 + rg * 8;
            float4 q0 = *(const float4*)p;
            float4 q1 = *(const float4*)(p + 4);
            float v[8] = {fmaxf(q0.x, 0.f), fmaxf(q0.y, 0.f),
                          fmaxf(q0.z, 0.f), fmaxf(q0.w, 0.f),
                          fmaxf(q1.x, 0.f), fmaxf(q1.y, 0.f),
                          fmaxf(q1.z, 0.f), fmaxf(q1.w, 0.f)};
            bf16x8 ah, am, al;
            split3pack8(v, ah, am, al);
            // products down to 2^-24: hh, hm, mh, mm, hl, lh
            Cacc[mm] = MFMA(ah, cbh[kc], Cacc[mm], 0, 0, 0);
            Cacc[mm] = MFMA(ah, cbm[kc], Cacc[mm], 0, 0, 0);
            Cacc[mm] = MFMA(am, cbh[kc], Cacc[mm], 0, 0, 0);
            Cacc[mm] = MFMA(am, cbm[kc], Cacc[mm], 0, 0, 0);
            Cacc[mm] = MFMA(ah, cbl[kc], Cacc[mm], 0, 0, 0);
            Cacc[mm] = MFMA(al, cbh[kc], Cacc[mm], 0, 0, 0);
        }
    }

    // ---------- 10 cycles ----------
    float e[2][4], wn[2][4];
    for (int it = 0; it < 10; ++it) {
        const int buf = it & 1;

        // e = s - C ; wn = e .* Rs ; stage W_t (transposed) and e_t into LDS.
        // Lane owns (X = 16m+4rg+r, Y): A[x][c] = W[c][x] -> write row Y,
        // c-quad = (m<<2)+rg. Waves cg and cg+4 together cover all 16 quads
        // of row Y (m 0..1 vs 2..3), disjoint -> no overlap.
        #pragma unroll
        for (int mm = 0; mm < 2; ++mm) {
            const int m = (mh << 1) + mm;
            #pragma unroll
            for (int r = 0; r < 4; ++r) {
                e[mm][r]  = s[mm][r] - Cacc[mm][r];
                wn[mm][r] = e[mm][r] * Rs[mm][r];
            }
            const int qw = ((m << 2) + rg) ^ cl;   // 16B-granular XOR swizzle
            Apk[buf][Y][qw] = split2pack(Wc[mm][0], Wc[mm][1], Wc[mm][2], Wc[mm][3]);
            Bpk[buf][Y][qw] = split2pack(e[mm][0],  e[mm][1],  e[mm][2],  e[mm][3]);
        }
        __syncthreads();

        // batched read burst: 12 ds_read_b128 (B x4, A x8 for this m-half)
        int4 br[2][2], arr[2][2][2];
        #pragma unroll
        for (int kc = 0; kc < 2; ++kc) {
            const int q0 = (kc << 3) + (rg << 1);
            br[kc][0] = Bpk[buf][Y][q0 ^ cl];
            br[kc][1] = Bpk[buf][Y][(q0 + 1) ^ cl];
            #pragma unroll
            for (int mm = 0; mm < 2; ++mm) {
                const int row = (((mh << 1) + mm) << 4) + cl;
                arr[kc][mm][0] = Apk[buf][row][q0 ^ cl];
                arr[kc][mm][1] = Apk[buf][row][(q0 + 1) ^ cl];
            }
        }

        // MFMA chain (per-accumulator order identical to R5/R6:
        // kc0 hh,hl,lh ; kc1 hh,hl,lh -> bit-identical numerics)
        f32x4 g[2];
        #pragma unroll
        for (int mm = 0; mm < 2; ++mm) g[mm] = (f32x4){0.f, 0.f, 0.f, 0.f};

        #pragma unroll
        for (int kc = 0; kc < 2; ++kc) {
            bf16x8 bh = mkfrag(br[kc][0].x, br[kc][0].y, br[kc][1].x, br[kc][1].y);
            bf16x8 bl = mkfrag(br[kc][0].z, br[kc][0].w, br[kc][1].z, br[kc][1].w);
            #pragma unroll
            for (int mm = 0; mm < 2; ++mm) {
                bf16x8 ah = mkfrag(arr[kc][mm][0].x, arr[kc][mm][0].y,
                                   arr[kc][mm][1].x, arr[kc][mm][1].y);
                bf16x8 al = mkfrag(arr[kc][mm][0].z, arr[kc][mm][0].w,
                                   arr[kc][mm][1].z, arr[kc][mm][1].w);
                g[mm] = MFMA(ah, bh, g[mm], 0, 0, 0);   // hh
                g[mm] = MFMA(ah, bl, g[mm], 0, 0, 0);   // hl
                g[mm] = MFMA(al, bh, g[mm], 0, 0, 0);   // lh
            }
        }

        // s += LR * (relu'(s) - e) .* g ; W_{t+1} = wn
        #pragma unroll
        for (int mm = 0; mm < 2; ++mm)
            #pragma unroll
            for (int r = 0; r < 4; ++r) {
                float rp = s[mm][r] > 0.f ? 1.f : 0.f;
                s[mm][r] = fmaf(LRc * (rp - e[mm][r]), g[mm][r], s[mm][r]);
                Wc[mm][r] = wn[mm][r];
            }
        // double-buffered; the single barrier per iter orders read(buf) at t
        // before write(buf) at t+2 (all waves pass barrier t+1 in between).
    }

    // out[4096:8192] = W after 10 cycles (= wn of the last iter)
    #pragma unroll
    for (int mm = 0; mm < 2; ++mm)
        #pragma unroll
        for (int r = 0; r < 4; ++r)
            out[4096 + ((((mh << 1) + mm) << 4) + (rg << 2) + r) * 64 + Y] = wn[mm][r];
}

extern "C" void kernel_launch(void* const* d_in, const int* in_sizes, int n_in,
                              void* d_out, int out_size, void* d_ws, size_t ws_size,
                              hipStream_t stream) {
    const float* S  = (const float*)d_in[2];   // (15,64,64)
    const float* Wk = (const float*)d_in[4];   // (14,64,64)
    const float* Wg = (const float*)d_in[5];   // (64,64)
    float* out = (float*)d_out;                // 8192 floats
    pcn_kernel<<<2, 512, 0, stream>>>(S, Wk, Wg, out);
}